// Round 11
// baseline (434.279 us; speedup 1.0000x reference)
//
#include <hip/hip_runtime.h>
#include <stdint.h>

#define D_    10000
#define DP1   10001
#define NPAD2 10240      // 40 * 256 (padded vocab rows for GEMM1, N-tile 256)
#define LGW   10240      // padded logit-row width (bf16 workspace)
#define H_    1024
#define BL    4096       // B * L
#define CANDS 1024       // fused-fallback candidate capacity
#define GC    512        // candidate capacity (typ. 1-6 used)

typedef float  f32x4  __attribute__((ext_vector_type(4)));
typedef __bf16 bf16x8 __attribute__((ext_vector_type(8)));
typedef unsigned short u16;
typedef u16    u16x8  __attribute__((ext_vector_type(8)));

// ---------- bf16 helpers (round-to-nearest-even) ----------
__device__ __forceinline__ u16 f2bf(float x) {
    union { float f; unsigned u; } v; v.f = x;
    unsigned r = v.u + 0x7FFFu + ((v.u >> 16) & 1u);
    return (u16)(r >> 16);
}
__device__ __forceinline__ float bf2f(u16 b) {
    union { float f; unsigned u; } v; v.u = ((unsigned)b) << 16;
    return v.f;
}

// async global -> LDS, 16B per lane (HW: wave-uniform base + lane*16)
#define GLOAD_LDS16(gsrc, ldst)                                             \
    __builtin_amdgcn_global_load_lds(                                       \
        (__attribute__((address_space(1))) void*)(void*)(gsrc),             \
        (__attribute__((address_space(3))) void*)(void*)(ldst), 16, 0, 0)

// History:
// R3: LDS swizzle -> bank conflicts 0. R6: counted-vmcnt 2-phase (proven).
// R7: 4-phase 256^2 regressed. R8: sparse-gather replaced gemm2 (648us).
// R9/R10: spill disasters (WRITE_SIZE >> output = spill; 3 blocks/CU needs
//   <=85 regs/wave, acc64+frags32 ~ 106 -> never). R11: 517. R12/R13/R14:
//   neutral micro-fixes; "softmax slow" falsified; tail near-roofline.
// R15: bf16-only gemm1 + exact sparse finish: 503->389us. gemm1 119us
//   (30% MfmaUtil vs 41us floor), absmax unchanged 0.0156. gemm1 PARKED
//   (register-limited). Remaining: sim traffic 492MB fp32-logit path.
// R16 (this): logits stored as bf16 [4096][10240] (82MB not 164; the
//   accumulator is bf16-product precision anyway; extra rounding only
//   perturbs non-candidate p by <3e-9 absolute). Fuse softmax+gather into
//   softmax_finish_k: read bf16 logits, bf16-based stats + candidate set,
//   exact fp32 dots for candidates+default, write sim ONCE with exact
//   values patched, emit out. Traffic 492->330MB, one less launch.

// ---------- prep: fp32 -> bf16 (8 elements/thread) ----------
__global__ __launch_bounds__(256)
void split_desc_k(const float* __restrict__ desc, u16* __restrict__ hi) {
    size_t i = ((size_t)blockIdx.x * 256 + threadIdx.x) * 8;   // exactly BL*H_
    f32x4 x0 = *(const f32x4*)(desc + i);
    f32x4 x1 = *(const f32x4*)(desc + i + 4);
    u16x8 h;
#pragma unroll
    for (int e = 0; e < 4; e++) { h[e] = f2bf(x0[e]); h[4 + e] = f2bf(x1[e]); }
    *(u16x8*)(hi + i) = h;
}

__global__ __launch_bounds__(256)
void split_fv_k(const float* __restrict__ vocab, const float* __restrict__ defe,
                u16* __restrict__ hi) {
    size_t i = ((size_t)blockIdx.x * 256 + threadIdx.x) * 8;   // exactly NPAD2*H_
    int d = (int)(i >> 10);                                    // 8-chunk never crosses rows
    f32x4 x0 = {0.f, 0.f, 0.f, 0.f}, x1 = {0.f, 0.f, 0.f, 0.f};
    if (d < D_) {
        x0 = *(const f32x4*)(vocab + i);
        x1 = *(const f32x4*)(vocab + i + 4);
    } else if (d == D_) {
        int h = (int)(i & 1023);
        x0 = *(const f32x4*)(defe + h);
        x1 = *(const f32x4*)(defe + h + 4);
    }
    u16x8 h8;
#pragma unroll
    for (int e = 0; e < 4; e++) { h8[e] = f2bf(x0[e]); h8[4 + e] = f2bf(x1[e]); }
    *(u16x8*)(hi + i) = h8;
}

// ---------- GEMM1 (bf16-only): logits ~ desc @ full_vocab^T -> bf16 buffer ----------
// Tile 128(M) x 256(N), BK=32, 512 threads (8 waves, 2x4, 64x64/wave).
// LDS 48KB double-buffered; 2-deep prefetch, counted vmcnt(3). [R6 shape]

#define G1_MFMA(a, b, c) __builtin_amdgcn_mfma_f32_16x16x32_bf16((a), (b), (c), 0, 0, 0)

#define G1_STAGE(AhB, BhB, kk) do {                                         \
    GLOAD_LDS16(a_h  + (kk), (char*)(AhB) + tid16);                         \
    GLOAD_LDS16(b_h0 + (kk), (char*)(BhB) + tid16);                         \
    GLOAD_LDS16(b_h1 + (kk), (char*)(BhB) + tid16 + 8192);                  \
} while (0)

#define G1_ITER(AhB, BhB, t) do {                                           \
    bf16x8 afh[4], bfh[4];                                                  \
    _Pragma("unroll")                                                       \
    for (int i = 0; i < 4; i++) {                                           \
        afh[i] = *(const bf16x8*)&AhB[aoff[i]];                             \
        bfh[i] = *(const bf16x8*)&BhB[boff[i]];                             \
    }                                                                       \
    __builtin_amdgcn_s_setprio(1);                                          \
    _Pragma("unroll")                                                       \
    for (int i = 0; i < 2; i++)                                             \
        _Pragma("unroll")                                                   \
        for (int j = 0; j < 4; j++)                                         \
            acc[i][j] = G1_MFMA(afh[i], bfh[j], acc[i][j]);                 \
    __builtin_amdgcn_s_setprio(0);                                          \
    asm volatile("s_waitcnt lgkmcnt(0)" ::: "memory");                      \
    __builtin_amdgcn_s_barrier();                                           \
    if ((t) + 2 < 32) G1_STAGE(AhB, BhB, ((t) + 2) * 32);                   \
    __builtin_amdgcn_s_setprio(1);                                          \
    _Pragma("unroll")                                                       \
    for (int i = 2; i < 4; i++)                                             \
        _Pragma("unroll")                                                   \
        for (int j = 0; j < 4; j++)                                         \
            acc[i][j] = G1_MFMA(afh[i], bfh[j], acc[i][j]);                 \
    __builtin_amdgcn_s_setprio(0);                                          \
    if ((t) + 2 < 32)      asm volatile("s_waitcnt vmcnt(3)" ::: "memory"); \
    else if ((t) + 1 < 32) asm volatile("s_waitcnt vmcnt(0)" ::: "memory"); \
    __builtin_amdgcn_s_barrier();                                           \
} while (0)

__global__ __launch_bounds__(512, 2)
void gemm1_k(const u16* __restrict__ Ahg, const u16* __restrict__ Bhg,
             u16* __restrict__ Lg) {
    __shared__ u16 Ah0[128 * 32], Bh0[256 * 32];
    __shared__ u16 Ah1[128 * 32], Bh1[256 * 32];

    const int tid  = threadIdx.x;
    const int wave = tid >> 6, lane = tid & 63;
    const int wr = wave >> 2, wc = wave & 3;
    const int quad = lane >> 4, r16 = lane & 15;
    const int m0 = blockIdx.y * 128, n0 = blockIdx.x * 256;

    f32x4 zero = {0.f, 0.f, 0.f, 0.f};
    f32x4 acc[4][4];
#pragma unroll
    for (int i = 0; i < 4; i++)
#pragma unroll
        for (int j = 0; j < 4; j++) acc[i][j] = zero;

    const int arow = tid >> 2, achk = tid & 3;
    const int ascol = (achk ^ ((arow >> 1) & 3)) * 8;
    const u16* a_h = Ahg + (size_t)(m0 + arow) * H_ + ascol;
    const int brow0 = arow,        bscol0 = (achk ^ ((brow0 >> 1) & 3)) * 8;
    const int brow1 = 128 + arow,  bscol1 = (achk ^ ((brow1 >> 1) & 3)) * 8;
    const u16* b_h0 = Bhg + (size_t)(n0 + brow0) * H_ + bscol0;
    const u16* b_h1 = Bhg + (size_t)(n0 + brow1) * H_ + bscol1;
    const int tid16 = tid * 16;
    const int aswz = (r16 >> 1) & 3;

    int aoff[4], boff[4];
#pragma unroll
    for (int i = 0; i < 4; i++) {
        aoff[i] = (wr * 64 + i * 16 + r16) * 32 + ((quad ^ aswz) * 8);
        boff[i] = (wc * 64 + i * 16 + r16) * 32 + ((quad ^ aswz) * 8);
    }

    G1_STAGE(Ah0, Bh0, 0);
    G1_STAGE(Ah1, Bh1, 32);
    asm volatile("s_waitcnt vmcnt(3)" ::: "memory");
    __builtin_amdgcn_s_barrier();

    for (int t = 0; t < 32; t += 2) {
        G1_ITER(Ah0, Bh0, t);
        G1_ITER(Ah1, Bh1, t + 1);
    }

    // C/D layout: row = quad*4 + reg, col = lane&15; bf16 store, padded width
#pragma unroll
    for (int i = 0; i < 4; i++) {
        int gm = m0 + wr * 64 + i * 16 + quad * 4;
#pragma unroll
        for (int j = 0; j < 4; j++) {
            int gn = n0 + wc * 64 + j * 16 + r16;
#pragma unroll
            for (int reg = 0; reg < 4; reg++)
                Lg[(size_t)(gm + reg) * LGW + gn] = f2bf(acc[i][j][reg]);
        }
    }
}

// ---------- fused finish: softmax over bf16 logits + exact sparse fixup ----------
// One block per (b,l) row, 1024 threads. Thread t owns logit elems t*8..t*8+7
// (chunk A, all < 8192) and, for t<256, 8192+t*8.. (chunk B, masked past D_).
// Stats/probs from bf16 logits; candidates (e > sum*1e-8, typ 1-6/row) and
// the default slot get EXACT fp32 logits (wave-parallel dots) -> exact
// max/Z/p patched into sim; out = p_def*desc + sum p_c*vocab[d_c].
__global__ __launch_bounds__(1024)
void softmax_finish_k(const u16* __restrict__ Lg, float* __restrict__ sim,
                      const float* __restrict__ vocab, const float* __restrict__ defe,
                      const float* __restrict__ desc, float* __restrict__ out) {
    __shared__ float red[16];
    __shared__ int   cnt;
    __shared__ int   cidx[GC];
    __shared__ float lex[GC + 1];
    __shared__ float psh[GC + 1];
    const int tid = threadIdx.x;
    const int row = blockIdx.x;
    const u16* lrow = Lg + (size_t)row * LGW;
    float* rowp = sim + (size_t)row * DP1;
    const float* drow = desc + (size_t)row * H_;
    if (tid == 0) cnt = 0;

    const int iA = tid * 8;            // 0..8191, all < D_
    const int iB = 8192 + tid * 8;     // 8192..10239 (t<256), mask idx > D_
    float va[8], vb[8];
    {
        u16x8 ra = *(const u16x8*)(lrow + iA);
#pragma unroll
        for (int e = 0; e < 8; e++) va[e] = bf2f(ra[e]);
    }
    if (tid < 256) {
        u16x8 rb = *(const u16x8*)(lrow + iB);
#pragma unroll
        for (int e = 0; e < 8; e++) vb[e] = (iB + e <= D_) ? bf2f(rb[e]) : -3.4e38f;
    } else {
#pragma unroll
        for (int e = 0; e < 8; e++) vb[e] = -3.4e38f;
    }

    float mx = -3.4e38f;
#pragma unroll
    for (int e = 0; e < 8; e++) mx = fmaxf(mx, fmaxf(va[e], vb[e]));
#pragma unroll
    for (int off = 32; off; off >>= 1) mx = fmaxf(mx, __shfl_down(mx, off, 64));
    if ((tid & 63) == 0) red[tid >> 6] = mx;
    __syncthreads();
#pragma unroll
    for (int w = 0; w < 16; w++) mx = fmaxf(mx, red[w]);

    float s0 = 0.f;
#pragma unroll
    for (int e = 0; e < 8; e++) {
        va[e] = __expf(va[e] - mx); s0 += va[e];
        vb[e] = __expf(vb[e] - mx); s0 += vb[e];   // exp(-huge)=0 for masked
    }
#pragma unroll
    for (int off = 32; off; off >>= 1) s0 += __shfl_down(s0, off, 64);
    __syncthreads();                               // red[] reuse hazard
    if ((tid & 63) == 0) red[tid >> 6] = s0;
    __syncthreads();
    float sum = 0.f;
#pragma unroll
    for (int w = 0; w < 16; w++) sum += red[w];
    const float inv = 1.f / sum;
    const float thr = sum * 1e-8f;

    // candidate collection (d < D_ only; default handled separately)
#pragma unroll
    for (int e = 0; e < 8; e++)
        if (va[e] > thr) {
            int k = atomicAdd(&cnt, 1);
            if (k < GC) cidx[k] = iA + e;
        }
    if (tid < 256) {
#pragma unroll
        for (int e = 0; e < 8; e++) {
            int idx = iB + e;
            if (idx < D_ && vb[e] > thr) {
                int k = atomicAdd(&cnt, 1);
                if (k < GC) cidx[k] = idx;
            }
        }
    }
    __syncthreads();

    const int cnt0 = cnt;
    const bool ovf = cnt0 > GC;                    // never on this data
    const int cc = ovf ? GC : cnt0;
    const int lane = tid & 63, wv = tid >> 6;

    if (!ovf) {
        // exact fp32 logits: wave wv handles c = wv, wv+16, ...; c==cc => default
        for (int c = wv; c <= cc; c += 16) {
            const float* vrow = (c == cc) ? defe : (vocab + (size_t)cidx[c] * H_);
            float s = 0.f;
#pragma unroll
            for (int q = 0; q < 4; q++) {
                f32x4 dv = *(const f32x4*)(drow + (q * 64 + lane) * 4);
                f32x4 vv = *(const f32x4*)(vrow + (q * 64 + lane) * 4);
                s += dv[0] * vv[0] + dv[1] * vv[1] + dv[2] * vv[2] + dv[3] * vv[3];
            }
#pragma unroll
            for (int off = 32; off; off >>= 1) s += __shfl_down(s, off, 64);
            if (lane == 0) lex[c] = s;
        }
        __syncthreads();
        // exact max/Z over cc+1 entries (tiny; per-thread redundant from LDS)
        float m = -3.4e38f;
        for (int c = 0; c <= cc; c++) m = fmaxf(m, lex[c]);
        float Z = 0.f;
        for (int c = 0; c <= cc; c++) Z += __expf(lex[c] - m);
        const float invZ = 1.f / Z;
        for (int i = tid; i <= cc; i += 1024) psh[i] = __expf(lex[i] - m) * invZ;
        __syncthreads();
    }

    // single write pass: bf16-based p, candidate/default slots patched exact
    {
        f32x4 p0, p1;
#pragma unroll
        for (int e = 0; e < 8; e++) {
            float p = va[e] * inv;
            if (!ovf && va[e] > thr) {
                for (int c = 0; c < cc; c++)
                    if (cidx[c] == iA + e) { p = psh[c]; break; }
            }
            if (e < 4) p0[e] = p; else p1[e - 4] = p;
        }
        *(f32x4*)(rowp + iA) = p0;
        *(f32x4*)(rowp + iA + 4) = p1;
    }
    if (tid < 256) {
#pragma unroll
        for (int e = 0; e < 8; e++) {
            int idx = iB + e;
            if (idx <= D_) {
                float p = vb[e] * inv;
                if (idx == D_) { if (!ovf) p = psh[cc]; }
                else if (!ovf && vb[e] > thr) {
                    for (int c = 0; c < cc; c++)
                        if (cidx[c] == idx) { p = psh[c]; break; }
                }
                rowp[idx] = p;
            }
        }
    }

    // out: thread t owns H-column t
    float a;
    if (!ovf) {
        a = psh[cc] * drow[tid];
        for (int c = 0; c < cc; c++)
            a += psh[c] * vocab[(size_t)cidx[c] * H_ + tid];
    } else {
        // pathological fallback: full scan of bf16-based probs (block-uniform)
        __syncthreads();
        a = rowp[D_] * drow[tid];
        for (int d = 0; d < D_; d++) {
            float p = rowp[d];
            if (p > 1e-8f) a += p * vocab[(size_t)d * H_ + tid];
        }
    }
    out[(size_t)row * H_ + tid] = a;
}

// ---------- fallback (ws too small): exact fp32 logits + fused epilogue ----------
__global__ __launch_bounds__(256)
void naive_logits_k(const float* __restrict__ vocab, const float* __restrict__ desc,
                    const float* __restrict__ defe, float* __restrict__ sim) {
    int d = blockIdx.x * 256 + threadIdx.x;
    if (d >= DP1) return;
    const float* vr = (d < D_) ? (vocab + (size_t)d * H_) : defe;
    const float* dr = desc + (size_t)blockIdx.y * H_;
    float s = 0.f;
    for (int h = 0; h < H_; h++) s = fmaf(dr[h], vr[h], s);
    sim[(size_t)blockIdx.y * DP1 + d] = s;
}

__global__ __launch_bounds__(1024)
void softmax_gather_k(float* __restrict__ sim, const float* __restrict__ vocab,
                      const float* __restrict__ desc, float* __restrict__ out) {
    __shared__ float red[16];
    __shared__ float wslot;
    __shared__ int   cnt;
    __shared__ int   cidx[CANDS];
    __shared__ float cp[CANDS];
    const int tid = threadIdx.x;
    const int row = blockIdx.x;
    float* rowp = sim + (size_t)row * DP1;
    if (tid == 0) cnt = 0;

    const int a0 = (4 - (row & 3)) & 3;
    const int b0 = a0 + tid * 4;
    const int b1 = a0 + 4096 + tid * 4;
    const int b2 = a0 + 8192 + tid * 4;

    float vh = (tid < a0) ? rowp[tid] : -3.4e38f;
    f32x4 v0 = *(const f32x4*)(rowp + b0);
    f32x4 v1 = *(const f32x4*)(rowp + b1);
    f32x4 v2;
    if (b2 + 3 <= D_) {
        v2 = *(const f32x4*)(rowp + b2);
    } else {
#pragma unroll
        for (int e = 0; e < 4; e++)
            v2[e] = (b2 + e <= D_) ? rowp[b2 + e] : -3.4e38f;
    }

    float mx = vh;
#pragma unroll
    for (int e = 0; e < 4; e++) mx = fmaxf(mx, fmaxf(v0[e], fmaxf(v1[e], v2[e])));
#pragma unroll
    for (int off = 32; off; off >>= 1) mx = fmaxf(mx, __shfl_down(mx, off, 64));
    if ((tid & 63) == 0) red[tid >> 6] = mx;
    __syncthreads();
#pragma unroll
    for (int w = 0; w < 16; w++) mx = fmaxf(mx, red[w]);

    float s0 = 0.f;
    vh = __expf(vh - mx); s0 += vh;
#pragma unroll
    for (int e = 0; e < 4; e++) {
        v0[e] = __expf(v0[e] - mx); s0 += v0[e];
        v1[e] = __expf(v1[e] - mx); s0 += v1[e];
        v2[e] = __expf(v2[e] - mx); s0 += v2[e];
    }
#pragma unroll
    for (int off = 32; off; off >>= 1) s0 += __shfl_down(s0, off, 64);
    __syncthreads();
    if ((tid & 63) == 0) red[tid >> 6] = s0;
    __syncthreads();
    float sum = 0.f;
#pragma unroll
    for (int w = 0; w < 16; w++) sum += red[w];
    const float inv = 1.f / sum;
    const float thr = sum * 1e-7f;

    if (tid < a0) {
        float p = vh * inv;
        rowp[tid] = p;
        if (vh > thr) {
            int k = atomicAdd(&cnt, 1);
            if (k < CANDS) { cidx[k] = tid; cp[k] = p; }
        }
    }
    {
        f32x4 p0 = v0 * inv;
        *(f32x4*)(rowp + b0) = p0;
#pragma unroll
        for (int e = 0; e < 4; e++)
            if (v0[e] > thr) {
                int k = atomicAdd(&cnt, 1);
                if (k < CANDS) { cidx[k] = b0 + e; cp[k] = p0[e]; }
            }
        f32x4 p1 = v1 * inv;
        *(f32x4*)(rowp + b1) = p1;
#pragma unroll
        for (int e = 0; e < 4; e++)
            if (v1[e] > thr) {
                int k = atomicAdd(&cnt, 1);
                if (k < CANDS) { cidx[k] = b1 + e; cp[k] = p1[e]; }
            }
#pragma unroll
        for (int e = 0; e < 4; e++) {
            int idx = b2 + e;
            if (idx <= D_) {
                float p = v2[e] * inv;
                rowp[idx] = p;
                if (idx == D_) wslot = p;
                else if (v2[e] > thr) {
                    int k = atomicAdd(&cnt, 1);
                    if (k < CANDS) { cidx[k] = idx; cp[k] = p; }
                }
            }
        }
    }
    __syncthreads();

    const float w = wslot;
    float a = w * desc[(size_t)row * H_ + tid];
    if (cnt <= CANDS) {
        const int k = cnt;
        for (int c = 0; c < k; c++)
            a += cp[c] * vocab[(size_t)cidx[c] * H_ + tid];
    } else {
        const float pthr = thr * inv;
        for (int d = 0; d < D_; d++) {
            float p = rowp[d];
            if (p > pthr) a += p * vocab[(size_t)d * H_ + tid];
        }
    }
    out[(size_t)row * H_ + tid] = a;
}

extern "C" void kernel_launch(void* const* d_in, const int* in_sizes, int n_in,
                              void* d_out, int out_size, void* d_ws, size_t ws_size,
                              hipStream_t stream) {
    (void)in_sizes; (void)n_in; (void)out_size;
    const float* vocab = (const float*)d_in[0];
    const float* desc  = (const float*)d_in[1];
    const float* defe  = (const float*)d_in[2];
    float* out = (float*)d_out;                          // concept: [4096][1024]
    float* sim = out + (size_t)BL * H_;                  // sim:     [4096][10001]

    // ws layout (bytes):
    //   desc_bf @ 0          (8,388,608)
    //   fv_bf   @ 8,388,608  (20,971,520 = NPAD2*H_*2)
    //   Lg      @ 29,360,128 (83,886,080 = BL*LGW*2)  -> REQ = 113,246,208
    const size_t REQ = 113246208ull;
    char* ws = (char*)d_ws;

    if (ws_size >= REQ) {
        u16* dhi = (u16*)(ws + 0);
        u16* fhi = (u16*)(ws + 8388608);
        u16* Lg  = (u16*)(ws + 29360128);

        split_desc_k<<<2048, 256, 0, stream>>>(desc, dhi);
        split_fv_k<<<5120, 256, 0, stream>>>(vocab, defe, fhi);
        gemm1_k<<<dim3(40, 32), 512, 0, stream>>>(dhi, fhi, Lg);
        softmax_finish_k<<<4096, 1024, 0, stream>>>(Lg, sim, vocab, defe, desc, out);
    } else {
        naive_logits_k<<<dim3(40, BL), 256, 0, stream>>>(vocab, desc, defe, sim);
        softmax_gather_k<<<4096, 1024, 0, stream>>>(sim, vocab, desc, out);
    }
}

// Round 12
// 410.629 us; speedup vs baseline: 1.0576x; 1.0576x over previous
//
#include <hip/hip_runtime.h>
#include <stdint.h>

#define D_    10000
#define DP1   10001
#define NPAD2 10240      // 40 * 256 (padded vocab rows for GEMM1, N-tile 256)
#define H_    1024
#define BL    4096       // B * L
#define NPB   160        // partial-LSE columns per row (40 n-blocks x 4 waves)
#define CANDS 1024       // fused-fallback candidate capacity
#define GC    512        // candidate capacity (typ. 1-6 used)

typedef float  f32x4  __attribute__((ext_vector_type(4)));
typedef __bf16 bf16x8 __attribute__((ext_vector_type(8)));
typedef unsigned short u16;
typedef u16    u16x8  __attribute__((ext_vector_type(8)));

// ---------- bf16 helpers (round-to-nearest-even) ----------
__device__ __forceinline__ u16 f2bf(float x) {
    union { float f; unsigned u; } v; v.f = x;
    unsigned r = v.u + 0x7FFFu + ((v.u >> 16) & 1u);
    return (u16)(r >> 16);
}

// async global -> LDS, 16B per lane (HW: wave-uniform base + lane*16)
#define GLOAD_LDS16(gsrc, ldst)                                             \
    __builtin_amdgcn_global_load_lds(                                       \
        (__attribute__((address_space(1))) void*)(void*)(gsrc),             \
        (__attribute__((address_space(3))) void*)(void*)(ldst), 16, 0, 0)

// History:
// R3 swizzle: bank conflicts 0. R6 counted-vmcnt 2-phase: proven. R7 4-phase
//   256^2: regressed. R8 sparse-gather: 648. R9/R10 spill (WRITE>>out).
// R11 517. R12/R13/R14 neutral micro-fixes.
// R15: bf16-only gemm1 (119us proven, fp32 sim epilogue) + exact sparse
//   finish: 389us. absmax 0.0156.
// R16: bf16-logit buffer + fused finish: REGRESSED 434. Learned: (a) the
//   2-byte scattered epilogue store cost gemm1 ~+35us -> fp32 epilogue
//   reverted; (b) finish is ~150us in EVERY variant regardless of traffic
//   (295 vs 492MB) -> LATENCY-CHAIN bound (serial block-wide reductions,
//   2 blocks/CU resident), not BW.
// R17 (this): kill the chain at the source. gemm1 epilogue computes
//   per-wave partial LSE (m,s) over its 64-col stripe (logits already in
//   regs; 128 shuffles + 64 exp ~ +3-5us) -> [4096][160] float2 (5MB).
//   Finish: combine partials -> exact M,Z (1.3KB, 2 syncs), ONE streaming
//   pass p=exp(l-M)*invZ + cand detect, then R15's exact-dot fixup + out.
//   256-thread blocks, ~40 VGPR -> 6+ blocks/CU of latency overlap.

// ---------- prep: fp32 -> bf16 (8 elements/thread) ----------
__global__ __launch_bounds__(256)
void split_desc_k(const float* __restrict__ desc, u16* __restrict__ hi) {
    size_t i = ((size_t)blockIdx.x * 256 + threadIdx.x) * 8;   // exactly BL*H_
    f32x4 x0 = *(const f32x4*)(desc + i);
    f32x4 x1 = *(const f32x4*)(desc + i + 4);
    u16x8 h;
#pragma unroll
    for (int e = 0; e < 4; e++) { h[e] = f2bf(x0[e]); h[4 + e] = f2bf(x1[e]); }
    *(u16x8*)(hi + i) = h;
}

__global__ __launch_bounds__(256)
void split_fv_k(const float* __restrict__ vocab, const float* __restrict__ defe,
                u16* __restrict__ hi) {
    size_t i = ((size_t)blockIdx.x * 256 + threadIdx.x) * 8;   // exactly NPAD2*H_
    int d = (int)(i >> 10);                                    // 8-chunk never crosses rows
    f32x4 x0 = {0.f, 0.f, 0.f, 0.f}, x1 = {0.f, 0.f, 0.f, 0.f};
    if (d < D_) {
        x0 = *(const f32x4*)(vocab + i);
        x1 = *(const f32x4*)(vocab + i + 4);
    } else if (d == D_) {
        int h = (int)(i & 1023);
        x0 = *(const f32x4*)(defe + h);
        x1 = *(const f32x4*)(defe + h + 4);
    }
    u16x8 h8;
#pragma unroll
    for (int e = 0; e < 4; e++) { h8[e] = f2bf(x0[e]); h8[4 + e] = f2bf(x1[e]); }
    *(u16x8*)(hi + i) = h8;
}

// ---------- GEMM1 (bf16-only): logits -> fp32 sim + per-wave partial LSE ----------
// Tile 128(M) x 256(N), BK=32, 512 threads (8 waves, 2x4, 64x64/wave).
// LDS 48KB double-buffered; 2-deep prefetch, counted vmcnt(3). [R15 proven]

#define G1_MFMA(a, b, c) __builtin_amdgcn_mfma_f32_16x16x32_bf16((a), (b), (c), 0, 0, 0)

#define G1_STAGE(AhB, BhB, kk) do {                                         \
    GLOAD_LDS16(a_h  + (kk), (char*)(AhB) + tid16);                         \
    GLOAD_LDS16(b_h0 + (kk), (char*)(BhB) + tid16);                         \
    GLOAD_LDS16(b_h1 + (kk), (char*)(BhB) + tid16 + 8192);                  \
} while (0)

#define G1_ITER(AhB, BhB, t) do {                                           \
    bf16x8 afh[4], bfh[4];                                                  \
    _Pragma("unroll")                                                       \
    for (int i = 0; i < 4; i++) {                                           \
        afh[i] = *(const bf16x8*)&AhB[aoff[i]];                             \
        bfh[i] = *(const bf16x8*)&BhB[boff[i]];                             \
    }                                                                       \
    __builtin_amdgcn_s_setprio(1);                                          \
    _Pragma("unroll")                                                       \
    for (int i = 0; i < 2; i++)                                             \
        _Pragma("unroll")                                                   \
        for (int j = 0; j < 4; j++)                                         \
            acc[i][j] = G1_MFMA(afh[i], bfh[j], acc[i][j]);                 \
    __builtin_amdgcn_s_setprio(0);                                          \
    asm volatile("s_waitcnt lgkmcnt(0)" ::: "memory");                      \
    __builtin_amdgcn_s_barrier();                                           \
    if ((t) + 2 < 32) G1_STAGE(AhB, BhB, ((t) + 2) * 32);                   \
    __builtin_amdgcn_s_setprio(1);                                          \
    _Pragma("unroll")                                                       \
    for (int i = 2; i < 4; i++)                                             \
        _Pragma("unroll")                                                   \
        for (int j = 0; j < 4; j++)                                         \
            acc[i][j] = G1_MFMA(afh[i], bfh[j], acc[i][j]);                 \
    __builtin_amdgcn_s_setprio(0);                                          \
    if ((t) + 2 < 32)      asm volatile("s_waitcnt vmcnt(3)" ::: "memory"); \
    else if ((t) + 1 < 32) asm volatile("s_waitcnt vmcnt(0)" ::: "memory"); \
    __builtin_amdgcn_s_barrier();                                           \
} while (0)

__global__ __launch_bounds__(512, 2)
void gemm1_k(const u16* __restrict__ Ahg, const u16* __restrict__ Bhg,
             float* __restrict__ C, float* __restrict__ Pt) {
    __shared__ u16 Ah0[128 * 32], Bh0[256 * 32];
    __shared__ u16 Ah1[128 * 32], Bh1[256 * 32];

    const int tid  = threadIdx.x;
    const int wave = tid >> 6, lane = tid & 63;
    const int wr = wave >> 2, wc = wave & 3;
    const int quad = lane >> 4, r16 = lane & 15;
    const int m0 = blockIdx.y * 128, n0 = blockIdx.x * 256;

    f32x4 zero = {0.f, 0.f, 0.f, 0.f};
    f32x4 acc[4][4];
#pragma unroll
    for (int i = 0; i < 4; i++)
#pragma unroll
        for (int j = 0; j < 4; j++) acc[i][j] = zero;

    const int arow = tid >> 2, achk = tid & 3;
    const int ascol = (achk ^ ((arow >> 1) & 3)) * 8;
    const u16* a_h = Ahg + (size_t)(m0 + arow) * H_ + ascol;
    const int brow0 = arow,        bscol0 = (achk ^ ((brow0 >> 1) & 3)) * 8;
    const int brow1 = 128 + arow,  bscol1 = (achk ^ ((brow1 >> 1) & 3)) * 8;
    const u16* b_h0 = Bhg + (size_t)(n0 + brow0) * H_ + bscol0;
    const u16* b_h1 = Bhg + (size_t)(n0 + brow1) * H_ + bscol1;
    const int tid16 = tid * 16;
    const int aswz = (r16 >> 1) & 3;

    int aoff[4], boff[4];
#pragma unroll
    for (int i = 0; i < 4; i++) {
        aoff[i] = (wr * 64 + i * 16 + r16) * 32 + ((quad ^ aswz) * 8);
        boff[i] = (wc * 64 + i * 16 + r16) * 32 + ((quad ^ aswz) * 8);
    }

    G1_STAGE(Ah0, Bh0, 0);
    G1_STAGE(Ah1, Bh1, 32);
    asm volatile("s_waitcnt vmcnt(3)" ::: "memory");
    __builtin_amdgcn_s_barrier();

    for (int t = 0; t < 32; t += 2) {
        G1_ITER(Ah0, Bh0, t);
        G1_ITER(Ah1, Bh1, t + 1);
    }

    // C-write (fp32, proven) + per-wave partial LSE over this wave's 64 cols
#pragma unroll
    for (int i = 0; i < 4; i++) {
        int gm = m0 + wr * 64 + i * 16 + quad * 4;
#pragma unroll
        for (int j = 0; j < 4; j++) {
            int gn = n0 + wc * 64 + j * 16 + r16;
            if (gn < DP1) {
#pragma unroll
                for (int reg = 0; reg < 4; reg++)
                    C[(size_t)(gm + reg) * DP1 + gn] = acc[i][j][reg];
            }
        }
    }
    const int pcol = blockIdx.x * 4 + wc;          // 0..159
#pragma unroll
    for (int i = 0; i < 4; i++) {
#pragma unroll
        for (int reg = 0; reg < 4; reg++) {
            float m = -3.4e38f;
#pragma unroll
            for (int j = 0; j < 4; j++) {
                int gn = n0 + wc * 64 + j * 16 + r16;
                if (gn < DP1) m = fmaxf(m, acc[i][j][reg]);
            }
#pragma unroll
            for (int off = 1; off < 16; off <<= 1)
                m = fmaxf(m, __shfl_xor(m, off, 64));
            float s = 0.f;
#pragma unroll
            for (int j = 0; j < 4; j++) {
                int gn = n0 + wc * 64 + j * 16 + r16;
                if (gn < DP1) s += __expf(acc[i][j][reg] - m);
            }
#pragma unroll
            for (int off = 1; off < 16; off <<= 1)
                s += __shfl_xor(s, off, 64);
            if (r16 == 0) {
                int grow = m0 + wr * 64 + i * 16 + quad * 4 + reg;
                float2 v; v.x = m; v.y = s;
                *(float2*)(Pt + ((size_t)grow * NPB + pcol) * 2) = v;
            }
        }
    }
}

// ---------- finish: combine partials -> exact M,Z; stream probs; exact fixup ----------
// One block per row, 256 threads. No row-wide data reductions: M,Z come from
// the 160 partials (1.3KB). Stream pass: p = exp(l-M)*invZ, write, cand
// detect (p > 1e-8). Then exact fp32 dots for cands + default (R15-proven),
// patch sim slots, emit out.
__global__ __launch_bounds__(256)
void softmax_finish_k(float* __restrict__ sim, const float* __restrict__ Pt,
                      const float* __restrict__ vocab, const float* __restrict__ defe,
                      const float* __restrict__ desc, float* __restrict__ out) {
    __shared__ float red[8];
    __shared__ int   cnt;
    __shared__ int   cidx[GC];
    __shared__ float lex[GC + 1];
    __shared__ float psh[GC + 1];
    const int tid = threadIdx.x;
    const int row = blockIdx.x;
    float* rowp = sim + (size_t)row * DP1;
    const float* drow = desc + (size_t)row * H_;
    const int lane = tid & 63, wv = tid >> 6;
    if (tid == 0) cnt = 0;

    // 1. exact M, Z from 160 partials
    float pm = -3.4e38f, ps = 0.f;
    if (tid < NPB) {
        float2 v = *(const float2*)(Pt + ((size_t)row * NPB + tid) * 2);
        pm = v.x; ps = v.y;
    }
    float mt = pm;
#pragma unroll
    for (int off = 32; off; off >>= 1) mt = fmaxf(mt, __shfl_down(mt, off, 64));
    if (lane == 0) red[wv] = mt;
    __syncthreads();
    const float M = fmaxf(fmaxf(red[0], red[1]), fmaxf(red[2], red[3]));
    float zt = (tid < NPB) ? __expf(pm - M) * ps : 0.f;
#pragma unroll
    for (int off = 32; off; off >>= 1) zt += __shfl_down(zt, off, 64);
    if (lane == 0) red[4 + wv] = zt;       // distinct slots: no hazard with red[0..3]
    __syncthreads();
    const float Z = red[4] + red[5] + red[6] + red[7];
    const float invZ = 1.f / Z;

    // 2. one streaming pass: logits -> probs, cand detect (p > 1e-8)
#pragma unroll
    for (int s = 0; s < 9; s++) {
        f32x4 l = *(const f32x4*)(rowp + s * 1024 + tid * 4);
        f32x4 p;
#pragma unroll
        for (int e = 0; e < 4; e++) p[e] = __expf(l[e] - M) * invZ;
        *(f32x4*)(rowp + s * 1024 + tid * 4) = p;
#pragma unroll
        for (int e = 0; e < 4; e++)
            if (p[e] > 1e-8f) {
                int k = atomicAdd(&cnt, 1);
                if (k < GC) cidx[k] = s * 1024 + tid * 4 + e;
            }
    }
    {
        const int base = 9216 + tid * 4;
#pragma unroll
        for (int e = 0; e < 4; e++) {
            int idx = base + e;
            if (idx <= D_) {
                float p = __expf(rowp[idx] - M) * invZ;
                rowp[idx] = p;                    // D_ slot patched exactly below
                if (idx < D_ && p > 1e-8f) {
                    int k = atomicAdd(&cnt, 1);
                    if (k < GC) cidx[k] = idx;
                }
            }
        }
    }
    __syncthreads();

    // 3. exact fp32 fixup for candidates + default (R15-proven)
    const int cnt0 = cnt;
    const bool ovf = cnt0 > GC;                   // never on this data
    const int cc = ovf ? GC : cnt0;
    if (!ovf) {
        for (int c = wv; c <= cc; c += 4) {
            const float* vrow = (c == cc) ? defe : (vocab + (size_t)cidx[c] * H_);
            float s = 0.f;
#pragma unroll
            for (int q = 0; q < 4; q++) {
                f32x4 dv = *(const f32x4*)(drow + (q * 64 + lane) * 4);
                f32x4 vv = *(const f32x4*)(vrow + (q * 64 + lane) * 4);
                s += dv[0] * vv[0] + dv[1] * vv[1] + dv[2] * vv[2] + dv[3] * vv[3];
            }
#pragma unroll
            for (int off = 32; off; off >>= 1) s += __shfl_down(s, off, 64);
            if (lane == 0) lex[c] = s;
        }
        __syncthreads();
        float m2 = -3.4e38f;
        for (int c = 0; c <= cc; c++) m2 = fmaxf(m2, lex[c]);
        float Z2 = 0.f;
        for (int c = 0; c <= cc; c++) Z2 += __expf(lex[c] - m2);
        const float iZ2 = 1.f / Z2;
        for (int i = tid; i <= cc; i += 256) psh[i] = __expf(lex[i] - m2) * iZ2;
        __syncthreads();
        for (int c = tid; c < cc; c += 256) rowp[cidx[c]] = psh[c];
        if (tid == 0) rowp[D_] = psh[cc];

        f32x4 a = psh[cc] * ((const f32x4*)drow)[tid];
        for (int c = 0; c < cc; c++)
            a += psh[c] * ((const f32x4*)(vocab + (size_t)cidx[c] * H_))[tid];
        ((f32x4*)(out + (size_t)row * H_))[tid] = a;
    } else {
        // pathological fallback: probs already streamed into rowp
        f32x4 a = rowp[D_] * ((const f32x4*)drow)[tid];
        for (int d = 0; d < D_; d++) {
            float p = rowp[d];
            if (p > 1e-8f) a += p * ((const f32x4*)(vocab + (size_t)d * H_))[tid];
        }
        ((f32x4*)(out + (size_t)row * H_))[tid] = a;
    }
}

// ---------- fallback (ws too small): exact fp32 logits + fused epilogue ----------
__global__ __launch_bounds__(256)
void naive_logits_k(const float* __restrict__ vocab, const float* __restrict__ desc,
                    const float* __restrict__ defe, float* __restrict__ sim) {
    int d = blockIdx.x * 256 + threadIdx.x;
    if (d >= DP1) return;
    const float* vr = (d < D_) ? (vocab + (size_t)d * H_) : defe;
    const float* dr = desc + (size_t)blockIdx.y * H_;
    float s = 0.f;
    for (int h = 0; h < H_; h++) s = fmaf(dr[h], vr[h], s);
    sim[(size_t)blockIdx.y * DP1 + d] = s;
}

__global__ __launch_bounds__(1024)
void softmax_gather_k(float* __restrict__ sim, const float* __restrict__ vocab,
                      const float* __restrict__ desc, float* __restrict__ out) {
    __shared__ float red[16];
    __shared__ float wslot;
    __shared__ int   cnt;
    __shared__ int   cidx[CANDS];
    __shared__ float cp[CANDS];
    const int tid = threadIdx.x;
    const int row = blockIdx.x;
    float* rowp = sim + (size_t)row * DP1;
    if (tid == 0) cnt = 0;

    const int a0 = (4 - (row & 3)) & 3;
    const int b0 = a0 + tid * 4;
    const int b1 = a0 + 4096 + tid * 4;
    const int b2 = a0 + 8192 + tid * 4;

    float vh = (tid < a0) ? rowp[tid] : -3.4e38f;
    f32x4 v0 = *(const f32x4*)(rowp + b0);
    f32x4 v1 = *(const f32x4*)(rowp + b1);
    f32x4 v2;
    if (b2 + 3 <= D_) {
        v2 = *(const f32x4*)(rowp + b2);
    } else {
#pragma unroll
        for (int e = 0; e < 4; e++)
            v2[e] = (b2 + e <= D_) ? rowp[b2 + e] : -3.4e38f;
    }

    float mx = vh;
#pragma unroll
    for (int e = 0; e < 4; e++) mx = fmaxf(mx, fmaxf(v0[e], fmaxf(v1[e], v2[e])));
#pragma unroll
    for (int off = 32; off; off >>= 1) mx = fmaxf(mx, __shfl_down(mx, off, 64));
    if ((tid & 63) == 0) red[tid >> 6] = mx;
    __syncthreads();
#pragma unroll
    for (int w = 0; w < 16; w++) mx = fmaxf(mx, red[w]);

    float s0 = 0.f;
    vh = __expf(vh - mx); s0 += vh;
#pragma unroll
    for (int e = 0; e < 4; e++) {
        v0[e] = __expf(v0[e] - mx); s0 += v0[e];
        v1[e] = __expf(v1[e] - mx); s0 += v1[e];
        v2[e] = __expf(v2[e] - mx); s0 += v2[e];
    }
#pragma unroll
    for (int off = 32; off; off >>= 1) s0 += __shfl_down(s0, off, 64);
    __syncthreads();
    if ((tid & 63) == 0) red[tid >> 6] = s0;
    __syncthreads();
    float sum = 0.f;
#pragma unroll
    for (int w = 0; w < 16; w++) sum += red[w];
    const float inv = 1.f / sum;
    const float thr = sum * 1e-7f;

    if (tid < a0) {
        float p = vh * inv;
        rowp[tid] = p;
        if (vh > thr) {
            int k = atomicAdd(&cnt, 1);
            if (k < CANDS) { cidx[k] = tid; cp[k] = p; }
        }
    }
    {
        f32x4 p0 = v0 * inv;
        *(f32x4*)(rowp + b0) = p0;
#pragma unroll
        for (int e = 0; e < 4; e++)
            if (v0[e] > thr) {
                int k = atomicAdd(&cnt, 1);
                if (k < CANDS) { cidx[k] = b0 + e; cp[k] = p0[e]; }
            }
        f32x4 p1 = v1 * inv;
        *(f32x4*)(rowp + b1) = p1;
#pragma unroll
        for (int e = 0; e < 4; e++)
            if (v1[e] > thr) {
                int k = atomicAdd(&cnt, 1);
                if (k < CANDS) { cidx[k] = b1 + e; cp[k] = p1[e]; }
            }
#pragma unroll
        for (int e = 0; e < 4; e++) {
            int idx = b2 + e;
            if (idx <= D_) {
                float p = v2[e] * inv;
                rowp[idx] = p;
                if (idx == D_) wslot = p;
                else if (v2[e] > thr) {
                    int k = atomicAdd(&cnt, 1);
                    if (k < CANDS) { cidx[k] = idx; cp[k] = p; }
                }
            }
        }
    }
    __syncthreads();

    const float w = wslot;
    float a = w * desc[(size_t)row * H_ + tid];
    if (cnt <= CANDS) {
        const int k = cnt;
        for (int c = 0; c < k; c++)
            a += cp[c] * vocab[(size_t)cidx[c] * H_ + tid];
    } else {
        const float pthr = thr * inv;
        for (int d = 0; d < D_; d++) {
            float p = rowp[d];
            if (p > pthr) a += p * vocab[(size_t)d * H_ + tid];
        }
    }
    out[(size_t)row * H_ + tid] = a;
}

extern "C" void kernel_launch(void* const* d_in, const int* in_sizes, int n_in,
                              void* d_out, int out_size, void* d_ws, size_t ws_size,
                              hipStream_t stream) {
    (void)in_sizes; (void)n_in; (void)out_size;
    const float* vocab = (const float*)d_in[0];
    const float* desc  = (const float*)d_in[1];
    const float* defe  = (const float*)d_in[2];
    float* out = (float*)d_out;                          // concept: [4096][1024]
    float* sim = out + (size_t)BL * H_;                  // sim:     [4096][10001]

    // ws layout (bytes):
    //   desc_bf @ 0          (8,388,608)
    //   fv_bf   @ 8,388,608  (20,971,520 = NPAD2*H_*2)
    //   Pt      @ 29,360,128 (5,242,880 = BL*NPB*8)   -> REQ = 34,603,008
    const size_t REQ = 34603008ull;
    char* ws = (char*)d_ws;

    if (ws_size >= REQ) {
        u16*   dhi = (u16*)(ws + 0);
        u16*   fhi = (u16*)(ws + 8388608);
        float* Pt  = (float*)(ws + 29360128);

        split_desc_k<<<2048, 256, 0, stream>>>(desc, dhi);
        split_fv_k<<<5120, 256, 0, stream>>>(vocab, defe, fhi);
        gemm1_k<<<dim3(40, 32), 512, 0, stream>>>(dhi, fhi, sim, Pt);
        softmax_finish_k<<<4096, 256, 0, stream>>>(sim, Pt, vocab, defe, desc, out);
    } else {
        naive_logits_k<<<dim3(40, BL), 256, 0, stream>>>(vocab, desc, defe, sim);
        softmax_gather_k<<<4096, 1024, 0, stream>>>(sim, vocab, desc, out);
    }
}

// Round 13
// 409.460 us; speedup vs baseline: 1.0606x; 1.0029x over previous
//
#include <hip/hip_runtime.h>
#include <stdint.h>

#define D_    10000
#define DP1   10001
#define NPAD2 10240      // 40 * 256 (padded vocab rows for GEMM1, N-tile 256)
#define H_    1024
#define BL    4096       // B * L
#define NPB   160        // partial-LSE columns per row (40 n-blocks x 4 waves)
#define CANDS 1024       // fused-fallback candidate capacity
#define GC    512        // candidate capacity (typ. 1-6 used)

typedef float  f32x4  __attribute__((ext_vector_type(4)));
typedef __bf16 bf16x8 __attribute__((ext_vector_type(8)));
typedef unsigned short u16;
typedef u16    u16x8  __attribute__((ext_vector_type(8)));

// ---------- bf16 helpers (round-to-nearest-even) ----------
__device__ __forceinline__ u16 f2bf(float x) {
    union { float f; unsigned u; } v; v.f = x;
    unsigned r = v.u + 0x7FFFu + ((v.u >> 16) & 1u);
    return (u16)(r >> 16);
}

// async global -> LDS, 16B per lane (HW: wave-uniform base + lane*16)
#define GLOAD_LDS16(gsrc, ldst)                                             \
    __builtin_amdgcn_global_load_lds(                                       \
        (__attribute__((address_space(1))) void*)(void*)(gsrc),             \
        (__attribute__((address_space(3))) void*)(void*)(ldst), 16, 0, 0)

// History:
// R3 swizzle: bank conflicts 0. R6 counted-vmcnt 2-phase: proven. R7 4-phase
//   256^2: regressed. R8 sparse-gather: 648. R9/R10 spill (WRITE>>out =
//   spill). R11 517. R12/R13/R14 neutral micro-fixes.
// R15: bf16-only gemm1 (119 proven) + exact sparse finish: 389. absmax
//   0.0156 held (candidates recomputed exactly in fp32).
// R16: bf16-logit buffer: regressed (2-byte scattered epilogue +35us on
//   gemm1; finish ~150 regardless of traffic -> latency-chain not BW).
// R17: partial-LSE in gemm1 epilogue (119->127) + fused finish: 410.
//   ACCOUNTING CLOSED: ~110-140us of every bench is FIXED harness overhead
//   (reset memsets + launch gaps; explains R12-R14 neutral results).
//   Kernel-side: splits 17 + gemm1 127 + tail ~125-140 vs ~80 floor.
// R18 (this): decompose tail into shape-matched kernels: rowstat_k (wave/
//   row: 160 partials -> exact M,1/Z; zero gcnt), prob_stream_k (PURE
//   streaming, grid(10,4096), no syncs: p=exp(l-M)*invZ, global-atomic cand
//   append), gather_k (R15-proven exact fixup + out). Splits fused into one
//   kernel. Pre-commit: total >= 395 -> tail at floor -> plateau.

// ---------- prep: fp32 -> bf16 (8 elements/thread), desc + fv in one ----------
__global__ __launch_bounds__(256)
void split_all_k(const float* __restrict__ desc, const float* __restrict__ vocab,
                 const float* __restrict__ defe,
                 u16* __restrict__ dhi, u16* __restrict__ fhi) {
    const int b = blockIdx.x;
    if (b < 2048) {                                   // desc: BL*H_ elements
        size_t i = ((size_t)b * 256 + threadIdx.x) * 8;
        f32x4 x0 = *(const f32x4*)(desc + i);
        f32x4 x1 = *(const f32x4*)(desc + i + 4);
        u16x8 h;
#pragma unroll
        for (int e = 0; e < 4; e++) { h[e] = f2bf(x0[e]); h[4 + e] = f2bf(x1[e]); }
        *(u16x8*)(dhi + i) = h;
    } else {                                          // full_vocab: NPAD2*H_
        size_t i = ((size_t)(b - 2048) * 256 + threadIdx.x) * 8;
        int d = (int)(i >> 10);                       // 8-chunk never crosses rows
        f32x4 x0 = {0.f, 0.f, 0.f, 0.f}, x1 = {0.f, 0.f, 0.f, 0.f};
        if (d < D_) {
            x0 = *(const f32x4*)(vocab + i);
            x1 = *(const f32x4*)(vocab + i + 4);
        } else if (d == D_) {
            int h = (int)(i & 1023);
            x0 = *(const f32x4*)(defe + h);
            x1 = *(const f32x4*)(defe + h + 4);
        }
        u16x8 h8;
#pragma unroll
        for (int e = 0; e < 4; e++) { h8[e] = f2bf(x0[e]); h8[4 + e] = f2bf(x1[e]); }
        *(u16x8*)(fhi + i) = h8;
    }
}

// ---------- GEMM1 (bf16-only): logits -> fp32 sim + per-wave partial LSE ----------
// Tile 128(M) x 256(N), BK=32, 512 threads (8 waves, 2x4, 64x64/wave).
// LDS 48KB double-buffered; 2-deep prefetch, counted vmcnt(3). [R17 proven 127us]

#define G1_MFMA(a, b, c) __builtin_amdgcn_mfma_f32_16x16x32_bf16((a), (b), (c), 0, 0, 0)

#define G1_STAGE(AhB, BhB, kk) do {                                         \
    GLOAD_LDS16(a_h  + (kk), (char*)(AhB) + tid16);                         \
    GLOAD_LDS16(b_h0 + (kk), (char*)(BhB) + tid16);                         \
    GLOAD_LDS16(b_h1 + (kk), (char*)(BhB) + tid16 + 8192);                  \
} while (0)

#define G1_ITER(AhB, BhB, t) do {                                           \
    bf16x8 afh[4], bfh[4];                                                  \
    _Pragma("unroll")                                                       \
    for (int i = 0; i < 4; i++) {                                           \
        afh[i] = *(const bf16x8*)&AhB[aoff[i]];                             \
        bfh[i] = *(const bf16x8*)&BhB[boff[i]];                             \
    }                                                                       \
    __builtin_amdgcn_s_setprio(1);                                          \
    _Pragma("unroll")                                                       \
    for (int i = 0; i < 2; i++)                                             \
        _Pragma("unroll")                                                   \
        for (int j = 0; j < 4; j++)                                         \
            acc[i][j] = G1_MFMA(afh[i], bfh[j], acc[i][j]);                 \
    __builtin_amdgcn_s_setprio(0);                                          \
    asm volatile("s_waitcnt lgkmcnt(0)" ::: "memory");                      \
    __builtin_amdgcn_s_barrier();                                           \
    if ((t) + 2 < 32) G1_STAGE(AhB, BhB, ((t) + 2) * 32);                   \
    __builtin_amdgcn_s_setprio(1);                                          \
    _Pragma("unroll")                                                       \
    for (int i = 2; i < 4; i++)                                             \
        _Pragma("unroll")                                                   \
        for (int j = 0; j < 4; j++)                                         \
            acc[i][j] = G1_MFMA(afh[i], bfh[j], acc[i][j]);                 \
    __builtin_amdgcn_s_setprio(0);                                          \
    if ((t) + 2 < 32)      asm volatile("s_waitcnt vmcnt(3)" ::: "memory"); \
    else if ((t) + 1 < 32) asm volatile("s_waitcnt vmcnt(0)" ::: "memory"); \
    __builtin_amdgcn_s_barrier();                                           \
} while (0)

__global__ __launch_bounds__(512, 2)
void gemm1_k(const u16* __restrict__ Ahg, const u16* __restrict__ Bhg,
             float* __restrict__ C, float* __restrict__ Pt) {
    __shared__ u16 Ah0[128 * 32], Bh0[256 * 32];
    __shared__ u16 Ah1[128 * 32], Bh1[256 * 32];

    const int tid  = threadIdx.x;
    const int wave = tid >> 6, lane = tid & 63;
    const int wr = wave >> 2, wc = wave & 3;
    const int quad = lane >> 4, r16 = lane & 15;
    const int m0 = blockIdx.y * 128, n0 = blockIdx.x * 256;

    f32x4 zero = {0.f, 0.f, 0.f, 0.f};
    f32x4 acc[4][4];
#pragma unroll
    for (int i = 0; i < 4; i++)
#pragma unroll
        for (int j = 0; j < 4; j++) acc[i][j] = zero;

    const int arow = tid >> 2, achk = tid & 3;
    const int ascol = (achk ^ ((arow >> 1) & 3)) * 8;
    const u16* a_h = Ahg + (size_t)(m0 + arow) * H_ + ascol;
    const int brow0 = arow,        bscol0 = (achk ^ ((brow0 >> 1) & 3)) * 8;
    const int brow1 = 128 + arow,  bscol1 = (achk ^ ((brow1 >> 1) & 3)) * 8;
    const u16* b_h0 = Bhg + (size_t)(n0 + brow0) * H_ + bscol0;
    const u16* b_h1 = Bhg + (size_t)(n0 + brow1) * H_ + bscol1;
    const int tid16 = tid * 16;
    const int aswz = (r16 >> 1) & 3;

    int aoff[4], boff[4];
#pragma unroll
    for (int i = 0; i < 4; i++) {
        aoff[i] = (wr * 64 + i * 16 + r16) * 32 + ((quad ^ aswz) * 8);
        boff[i] = (wc * 64 + i * 16 + r16) * 32 + ((quad ^ aswz) * 8);
    }

    G1_STAGE(Ah0, Bh0, 0);
    G1_STAGE(Ah1, Bh1, 32);
    asm volatile("s_waitcnt vmcnt(3)" ::: "memory");
    __builtin_amdgcn_s_barrier();

    for (int t = 0; t < 32; t += 2) {
        G1_ITER(Ah0, Bh0, t);
        G1_ITER(Ah1, Bh1, t + 1);
    }

    // C-write (fp32, proven) + per-wave partial LSE over this wave's 64 cols
#pragma unroll
    for (int i = 0; i < 4; i++) {
        int gm = m0 + wr * 64 + i * 16 + quad * 4;
#pragma unroll
        for (int j = 0; j < 4; j++) {
            int gn = n0 + wc * 64 + j * 16 + r16;
            if (gn < DP1) {
#pragma unroll
                for (int reg = 0; reg < 4; reg++)
                    C[(size_t)(gm + reg) * DP1 + gn] = acc[i][j][reg];
            }
        }
    }
    const int pcol = blockIdx.x * 4 + wc;          // 0..159
#pragma unroll
    for (int i = 0; i < 4; i++) {
#pragma unroll
        for (int reg = 0; reg < 4; reg++) {
            float m = -3.4e38f;
#pragma unroll
            for (int j = 0; j < 4; j++) {
                int gn = n0 + wc * 64 + j * 16 + r16;
                if (gn < DP1) m = fmaxf(m, acc[i][j][reg]);
            }
#pragma unroll
            for (int off = 1; off < 16; off <<= 1)
                m = fmaxf(m, __shfl_xor(m, off, 64));
            float s = 0.f;
#pragma unroll
            for (int j = 0; j < 4; j++) {
                int gn = n0 + wc * 64 + j * 16 + r16;
                if (gn < DP1) s += __expf(acc[i][j][reg] - m);
            }
#pragma unroll
            for (int off = 1; off < 16; off <<= 1)
                s += __shfl_xor(s, off, 64);
            if (r16 == 0) {
                int grow = m0 + wr * 64 + i * 16 + quad * 4 + reg;
                float2 v; v.x = m; v.y = s;
                *(float2*)(Pt + ((size_t)grow * NPB + pcol) * 2) = v;
            }
        }
    }
}

// ---------- rowstat: one wave per row; 160 partials -> exact (M, 1/Z); zero gcnt ----------
__global__ __launch_bounds__(256)
void rowstat_k(const float* __restrict__ Pt, float2* __restrict__ stats,
               int* __restrict__ gcnt) {
    const int tid = threadIdx.x, lane = tid & 63, wv = tid >> 6;
    const int row = blockIdx.x * 4 + wv;
    const float2* pp = (const float2*)Pt + (size_t)row * NPB;
    float2 p0 = pp[lane];
    float2 p1 = pp[lane + 64];
    float2 p2 = (lane < 32) ? pp[lane + 128] : p0;   // dup p0: no effect on max
    float m = fmaxf(fmaxf(p0.x, p1.x), p2.x);
#pragma unroll
    for (int off = 32; off; off >>= 1) m = fmaxf(m, __shfl_xor(m, off, 64));
    float z = __expf(p0.x - m) * p0.y + __expf(p1.x - m) * p1.y;
    if (lane < 32) z += __expf(p2.x - m) * p2.y;
#pragma unroll
    for (int off = 32; off; off >>= 1) z += __shfl_xor(z, off, 64);
    if (lane == 0) {
        float2 st; st.x = m; st.y = 1.f / z;
        stats[row] = st;
        gcnt[row] = 0;
    }
}

// ---------- prob_stream: pure streaming; p = exp(l-M)*invZ; cand append ----------
// grid (10, 4096) x 256; block x covers columns x*1024 + tid*4 (+0..3).
__global__ __launch_bounds__(256)
void prob_stream_k(float* __restrict__ sim, const float2* __restrict__ stats,
                   int* __restrict__ gcnt, int* __restrict__ gcidx) {
    const int row = blockIdx.y;
    const float2 st = stats[row];
    const float M = st.x, invZ = st.y;
    float* rowp = sim + (size_t)row * DP1;
    const int base = blockIdx.x * 1024 + threadIdx.x * 4;
    if (base + 3 <= D_) {
        f32x4 l = *(const f32x4*)(rowp + base);
        f32x4 p;
#pragma unroll
        for (int e = 0; e < 4; e++) p[e] = __expf(l[e] - M) * invZ;
        *(f32x4*)(rowp + base) = p;
#pragma unroll
        for (int e = 0; e < 4; e++)
            if (p[e] > 1e-8f && base + e < D_) {
                int k = atomicAdd(&gcnt[row], 1);
                if (k < GC) gcidx[(size_t)row * GC + k] = base + e;
            }
    } else if (base <= D_) {
#pragma unroll
        for (int e = 0; e < 4; e++) {
            int idx = base + e;
            if (idx <= D_) {
                float p = __expf(rowp[idx] - M) * invZ;
                rowp[idx] = p;                     // D_ slot patched exactly in gather
                if (idx < D_ && p > 1e-8f) {
                    int k = atomicAdd(&gcnt[row], 1);
                    if (k < GC) gcidx[(size_t)row * GC + k] = idx;
                }
            }
        }
    }
}

// ---------- gather: exact fp32 fixup for candidates + default; emit out ----------
__global__ __launch_bounds__(256)
void gather_k(float* __restrict__ sim, const int* __restrict__ gcnt,
              const int* __restrict__ gcidx,
              const float* __restrict__ vocab, const float* __restrict__ defe,
              const float* __restrict__ desc, float* __restrict__ out) {
    __shared__ int   cidx[GC];
    __shared__ float lex[GC + 1];
    __shared__ float psh[GC + 1];
    const int tid = threadIdx.x;
    const int row = blockIdx.x;
    const int cnt0 = gcnt[row];
    const bool ovf = cnt0 > GC;                    // never on this data
    const int cc = ovf ? GC : cnt0;
    float* rowp = sim + (size_t)row * DP1;
    const float* drow = desc + (size_t)row * H_;
    const int lane = tid & 63, wv = tid >> 6;

    for (int c = tid; c < cc; c += 256) cidx[c] = gcidx[(size_t)row * GC + c];
    __syncthreads();

    if (!ovf) {
        // exact fp32 logits: wave wv handles c = wv, wv+4, ...; c==cc => default
        for (int c = wv; c <= cc; c += 4) {
            const float* vrow = (c == cc) ? defe : (vocab + (size_t)cidx[c] * H_);
            float s = 0.f;
#pragma unroll
            for (int q = 0; q < 4; q++) {
                f32x4 dv = *(const f32x4*)(drow + (q * 64 + lane) * 4);
                f32x4 vv = *(const f32x4*)(vrow + (q * 64 + lane) * 4);
                s += dv[0] * vv[0] + dv[1] * vv[1] + dv[2] * vv[2] + dv[3] * vv[3];
            }
#pragma unroll
            for (int off = 32; off; off >>= 1) s += __shfl_down(s, off, 64);
            if (lane == 0) lex[c] = s;
        }
        __syncthreads();
        float m2 = -3.4e38f;
        for (int c = 0; c <= cc; c++) m2 = fmaxf(m2, lex[c]);
        float Z2 = 0.f;
        for (int c = 0; c <= cc; c++) Z2 += __expf(lex[c] - m2);
        const float iZ2 = 1.f / Z2;
        for (int i = tid; i <= cc; i += 256) psh[i] = __expf(lex[i] - m2) * iZ2;
        __syncthreads();
        for (int c = tid; c < cc; c += 256) rowp[cidx[c]] = psh[c];
        if (tid == 0) rowp[D_] = psh[cc];

        f32x4 a = psh[cc] * ((const f32x4*)drow)[tid];
        for (int c = 0; c < cc; c++)
            a += psh[c] * ((const f32x4*)(vocab + (size_t)cidx[c] * H_))[tid];
        ((f32x4*)(out + (size_t)row * H_))[tid] = a;
    } else {
        // pathological fallback: streamed probs already in rowp
        f32x4 a = rowp[D_] * ((const f32x4*)drow)[tid];
        for (int d = 0; d < D_; d++) {
            float p = rowp[d];
            if (p > 1e-8f) a += p * ((const f32x4*)(vocab + (size_t)d * H_))[tid];
        }
        ((f32x4*)(out + (size_t)row * H_))[tid] = a;
    }
}

// ---------- fallback (ws too small): exact fp32 logits + fused epilogue ----------
__global__ __launch_bounds__(256)
void naive_logits_k(const float* __restrict__ vocab, const float* __restrict__ desc,
                    const float* __restrict__ defe, float* __restrict__ sim) {
    int d = blockIdx.x * 256 + threadIdx.x;
    if (d >= DP1) return;
    const float* vr = (d < D_) ? (vocab + (size_t)d * H_) : defe;
    const float* dr = desc + (size_t)blockIdx.y * H_;
    float s = 0.f;
    for (int h = 0; h < H_; h++) s = fmaf(dr[h], vr[h], s);
    sim[(size_t)blockIdx.y * DP1 + d] = s;
}

__global__ __launch_bounds__(1024)
void softmax_gather_k(float* __restrict__ sim, const float* __restrict__ vocab,
                      const float* __restrict__ desc, float* __restrict__ out) {
    __shared__ float red[16];
    __shared__ float wslot;
    __shared__ int   cnt;
    __shared__ int   cidx[CANDS];
    __shared__ float cp[CANDS];
    const int tid = threadIdx.x;
    const int row = blockIdx.x;
    float* rowp = sim + (size_t)row * DP1;
    if (tid == 0) cnt = 0;

    const int a0 = (4 - (row & 3)) & 3;
    const int b0 = a0 + tid * 4;
    const int b1 = a0 + 4096 + tid * 4;
    const int b2 = a0 + 8192 + tid * 4;

    float vh = (tid < a0) ? rowp[tid] : -3.4e38f;
    f32x4 v0 = *(const f32x4*)(rowp + b0);
    f32x4 v1 = *(const f32x4*)(rowp + b1);
    f32x4 v2;
    if (b2 + 3 <= D_) {
        v2 = *(const f32x4*)(rowp + b2);
    } else {
#pragma unroll
        for (int e = 0; e < 4; e++)
            v2[e] = (b2 + e <= D_) ? rowp[b2 + e] : -3.4e38f;
    }

    float mx = vh;
#pragma unroll
    for (int e = 0; e < 4; e++) mx = fmaxf(mx, fmaxf(v0[e], fmaxf(v1[e], v2[e])));
#pragma unroll
    for (int off = 32; off; off >>= 1) mx = fmaxf(mx, __shfl_down(mx, off, 64));
    if ((tid & 63) == 0) red[tid >> 6] = mx;
    __syncthreads();
#pragma unroll
    for (int w = 0; w < 16; w++) mx = fmaxf(mx, red[w]);

    float s0 = 0.f;
    vh = __expf(vh - mx); s0 += vh;
#pragma unroll
    for (int e = 0; e < 4; e++) {
        v0[e] = __expf(v0[e] - mx); s0 += v0[e];
        v1[e] = __expf(v1[e] - mx); s0 += v1[e];
        v2[e] = __expf(v2[e] - mx); s0 += v2[e];
    }
#pragma unroll
    for (int off = 32; off; off >>= 1) s0 += __shfl_down(s0, off, 64);
    __syncthreads();
    if ((tid & 63) == 0) red[tid >> 6] = s0;
    __syncthreads();
    float sum = 0.f;
#pragma unroll
    for (int w = 0; w < 16; w++) sum += red[w];
    const float inv = 1.f / sum;
    const float thr = sum * 1e-7f;

    if (tid < a0) {
        float p = vh * inv;
        rowp[tid] = p;
        if (vh > thr) {
            int k = atomicAdd(&cnt, 1);
            if (k < CANDS) { cidx[k] = tid; cp[k] = p; }
        }
    }
    {
        f32x4 p0 = v0 * inv;
        *(f32x4*)(rowp + b0) = p0;
#pragma unroll
        for (int e = 0; e < 4; e++)
            if (v0[e] > thr) {
                int k = atomicAdd(&cnt, 1);
                if (k < CANDS) { cidx[k] = b0 + e; cp[k] = p0[e]; }
            }
        f32x4 p1 = v1 * inv;
        *(f32x4*)(rowp + b1) = p1;
#pragma unroll
        for (int e = 0; e < 4; e++)
            if (v1[e] > thr) {
                int k = atomicAdd(&cnt, 1);
                if (k < CANDS) { cidx[k] = b1 + e; cp[k] = p1[e]; }
            }
#pragma unroll
        for (int e = 0; e < 4; e++) {
            int idx = b2 + e;
            if (idx <= D_) {
                float p = v2[e] * inv;
                rowp[idx] = p;
                if (idx == D_) wslot = p;
                else if (v2[e] > thr) {
                    int k = atomicAdd(&cnt, 1);
                    if (k < CANDS) { cidx[k] = idx; cp[k] = p; }
                }
            }
        }
    }
    __syncthreads();

    const float w = wslot;
    float a = w * desc[(size_t)row * H_ + tid];
    if (cnt <= CANDS) {
        const int k = cnt;
        for (int c = 0; c < k; c++)
            a += cp[c] * vocab[(size_t)cidx[c] * H_ + tid];
    } else {
        const float pthr = thr * inv;
        for (int d = 0; d < D_; d++) {
            float p = rowp[d];
            if (p > pthr) a += p * vocab[(size_t)d * H_ + tid];
        }
    }
    out[(size_t)row * H_ + tid] = a;
}

extern "C" void kernel_launch(void* const* d_in, const int* in_sizes, int n_in,
                              void* d_out, int out_size, void* d_ws, size_t ws_size,
                              hipStream_t stream) {
    (void)in_sizes; (void)n_in; (void)out_size;
    const float* vocab = (const float*)d_in[0];
    const float* desc  = (const float*)d_in[1];
    const float* defe  = (const float*)d_in[2];
    float* out = (float*)d_out;                          // concept: [4096][1024]
    float* sim = out + (size_t)BL * H_;                  // sim:     [4096][10001]

    // ws layout (bytes):
    //   desc_bf @ 0          (8,388,608)
    //   fv_bf   @ 8,388,608  (20,971,520 = NPAD2*H_*2)
    //   Pt      @ 29,360,128 (5,242,880 = BL*NPB*8)
    //   gcnt    @ 34,603,008 (16,384)
    //   gcidx   @ 34,619,392 (8,388,608 = BL*GC*4)
    //   stats   @ 43,008,000 (32,768 = BL*8)        -> REQ = 43,040,768
    const size_t REQ = 43040768ull;
    char* ws = (char*)d_ws;

    if (ws_size >= REQ) {
        u16*    dhi   = (u16*)(ws + 0);
        u16*    fhi   = (u16*)(ws + 8388608);
        float*  Pt    = (float*)(ws + 29360128);
        int*    gcnt  = (int*)(ws + 34603008);
        int*    gcidx = (int*)(ws + 34619392);
        float2* stats = (float2*)(ws + 43008000);

        split_all_k<<<7168, 256, 0, stream>>>(desc, vocab, defe, dhi, fhi);
        gemm1_k<<<dim3(40, 32), 512, 0, stream>>>(dhi, fhi, sim, Pt);
        rowstat_k<<<1024, 256, 0, stream>>>(Pt, stats, gcnt);
        prob_stream_k<<<dim3(10, 4096), 256, 0, stream>>>(sim, stats, gcnt, gcidx);
        gather_k<<<4096, 256, 0, stream>>>(sim, gcnt, gcidx, vocab, defe, desc, out);
    } else {
        naive_logits_k<<<dim3(40, BL), 256, 0, stream>>>(vocab, desc, defe, sim);
        softmax_gather_k<<<4096, 1024, 0, stream>>>(sim, vocab, desc, out);
    }
}

// Round 14
// 392.330 us; speedup vs baseline: 1.1069x; 1.0437x over previous
//
#include <hip/hip_runtime.h>
#include <stdint.h>

#define D_    10000
#define DP1   10001
#define NPAD2 10240      // 40 * 256 (padded vocab rows for GEMM1, N-tile 256)
#define H_    1024
#define BL    4096       // B * L
#define CANDS 1024       // fused-fallback candidate capacity
#define GC    512        // candidate capacity (typ. 1-6 used)

typedef float  f32x4  __attribute__((ext_vector_type(4)));
typedef __bf16 bf16x8 __attribute__((ext_vector_type(8)));
typedef unsigned short u16;
typedef u16    u16x8  __attribute__((ext_vector_type(8)));

// ---------- bf16 helpers (round-to-nearest-even) ----------
__device__ __forceinline__ u16 f2bf(float x) {
    union { float f; unsigned u; } v; v.f = x;
    unsigned r = v.u + 0x7FFFu + ((v.u >> 16) & 1u);
    return (u16)(r >> 16);
}

// async global -> LDS, 16B per lane (HW: wave-uniform base + lane*16)
#define GLOAD_LDS16(gsrc, ldst)                                             \
    __builtin_amdgcn_global_load_lds(                                       \
        (__attribute__((address_space(1))) void*)(void*)(gsrc),             \
        (__attribute__((address_space(3))) void*)(void*)(ldst), 16, 0, 0)

// History:
// R3 swizzle: bank conflicts 0. R6 counted-vmcnt 2-phase: proven. R7 4-phase
//   256^2: regressed. R8 sparse-gather: 648. R9/R10 spill (WRITE>>out =
//   spill signature). R11 517. R12/R13/R14 neutral micro-fixes ("softmax
//   slow" falsified; ~150us of every bench is FIXED harness overhead).
// R15: bf16-only gemm1 (119us) + exact sparse finish: 389us = BEST.
//   absmax 0.0156 (candidates recomputed exactly in fp32).
// R16: bf16-logit buffer: regressed (scattered 2B epilogue +35us).
// R17/R18: partial-LSE epilogue (+11us on gemm1) + restructured tail:
//   410/409. DECISIVE: R18's zero-reduction streaming tail == R15's
//   reduction tail in cost -> the tail was ALREADY at floor (~52us sim
//   traffic + gather + fixed overhead). LSE epilogue bought nothing.
// R19 (this): consolidation revert to best-known: R15 gemm1 (no LSE
//   epilogue) + R15 softmax_cand/gather tail + R18's fused single split
//   (one less launch). Every piece bench-proven. Expected ~385.

// ---------- prep: fp32 -> bf16 (8 elements/thread), desc + fv in one ----------
__global__ __launch_bounds__(256)
void split_all_k(const float* __restrict__ desc, const float* __restrict__ vocab,
                 const float* __restrict__ defe,
                 u16* __restrict__ dhi, u16* __restrict__ fhi) {
    const int b = blockIdx.x;
    if (b < 2048) {                                   // desc: BL*H_ elements
        size_t i = ((size_t)b * 256 + threadIdx.x) * 8;
        f32x4 x0 = *(const f32x4*)(desc + i);
        f32x4 x1 = *(const f32x4*)(desc + i + 4);
        u16x8 h;
#pragma unroll
        for (int e = 0; e < 4; e++) { h[e] = f2bf(x0[e]); h[4 + e] = f2bf(x1[e]); }
        *(u16x8*)(dhi + i) = h;
    } else {                                          // full_vocab: NPAD2*H_
        size_t i = ((size_t)(b - 2048) * 256 + threadIdx.x) * 8;
        int d = (int)(i >> 10);                       // 8-chunk never crosses rows
        f32x4 x0 = {0.f, 0.f, 0.f, 0.f}, x1 = {0.f, 0.f, 0.f, 0.f};
        if (d < D_) {
            x0 = *(const f32x4*)(vocab + i);
            x1 = *(const f32x4*)(vocab + i + 4);
        } else if (d == D_) {
            int h = (int)(i & 1023);
            x0 = *(const f32x4*)(defe + h);
            x1 = *(const f32x4*)(defe + h + 4);
        }
        u16x8 h8;
#pragma unroll
        for (int e = 0; e < 4; e++) { h8[e] = f2bf(x0[e]); h8[4 + e] = f2bf(x1[e]); }
        *(u16x8*)(fhi + i) = h8;
    }
}

// ---------- GEMM1 (bf16-only): logits ~ desc @ full_vocab^T -> fp32 sim ----------
// Tile 128(M) x 256(N), BK=32, 512 threads (8 waves, 2x4, 64x64/wave).
// LDS 48KB double-buffered; 2-deep prefetch, counted vmcnt(3). [R15 proven 119us]

#define G1_MFMA(a, b, c) __builtin_amdgcn_mfma_f32_16x16x32_bf16((a), (b), (c), 0, 0, 0)

#define G1_STAGE(AhB, BhB, kk) do {                                         \
    GLOAD_LDS16(a_h  + (kk), (char*)(AhB) + tid16);                         \
    GLOAD_LDS16(b_h0 + (kk), (char*)(BhB) + tid16);                         \
    GLOAD_LDS16(b_h1 + (kk), (char*)(BhB) + tid16 + 8192);                  \
} while (0)

// phase 0 = {ds_read 8 frags, 8 MFMA (i=0,1), lgkmcnt(0), barrier}
// phase 1 = {STAGE t+2 -> this buffer, 8 MFMA (i=2,3), vmcnt(3), barrier}
// vmcnt(3): tile t+1's 3 loads complete; tile t+2's 3 stay in flight.
#define G1_ITER(AhB, BhB, t) do {                                           \
    bf16x8 afh[4], bfh[4];                                                  \
    _Pragma("unroll")                                                       \
    for (int i = 0; i < 4; i++) {                                           \
        afh[i] = *(const bf16x8*)&AhB[aoff[i]];                             \
        bfh[i] = *(const bf16x8*)&BhB[boff[i]];                             \
    }                                                                       \
    __builtin_amdgcn_s_setprio(1);                                          \
    _Pragma("unroll")                                                       \
    for (int i = 0; i < 2; i++)                                             \
        _Pragma("unroll")                                                   \
        for (int j = 0; j < 4; j++)                                         \
            acc[i][j] = G1_MFMA(afh[i], bfh[j], acc[i][j]);                 \
    __builtin_amdgcn_s_setprio(0);                                          \
    asm volatile("s_waitcnt lgkmcnt(0)" ::: "memory");                      \
    __builtin_amdgcn_s_barrier();                                           \
    if ((t) + 2 < 32) G1_STAGE(AhB, BhB, ((t) + 2) * 32);                   \
    __builtin_amdgcn_s_setprio(1);                                          \
    _Pragma("unroll")                                                       \
    for (int i = 2; i < 4; i++)                                             \
        _Pragma("unroll")                                                   \
        for (int j = 0; j < 4; j++)                                         \
            acc[i][j] = G1_MFMA(afh[i], bfh[j], acc[i][j]);                 \
    __builtin_amdgcn_s_setprio(0);                                          \
    if ((t) + 2 < 32)      asm volatile("s_waitcnt vmcnt(3)" ::: "memory"); \
    else if ((t) + 1 < 32) asm volatile("s_waitcnt vmcnt(0)" ::: "memory"); \
    __builtin_amdgcn_s_barrier();                                           \
} while (0)

__global__ __launch_bounds__(512, 2)
void gemm1_k(const u16* __restrict__ Ahg, const u16* __restrict__ Bhg,
             float* __restrict__ C) {
    __shared__ u16 Ah0[128 * 32], Bh0[256 * 32];
    __shared__ u16 Ah1[128 * 32], Bh1[256 * 32];

    const int tid  = threadIdx.x;
    const int wave = tid >> 6, lane = tid & 63;
    const int wr = wave >> 2, wc = wave & 3;
    const int quad = lane >> 4, r16 = lane & 15;
    const int m0 = blockIdx.y * 128, n0 = blockIdx.x * 256;

    f32x4 zero = {0.f, 0.f, 0.f, 0.f};
    f32x4 acc[4][4];
#pragma unroll
    for (int i = 0; i < 4; i++)
#pragma unroll
        for (int j = 0; j < 4; j++) acc[i][j] = zero;

    // staging: thread t covers row t>>2, chunk t&3 (swizzled source column)
    const int arow = tid >> 2, achk = tid & 3;
    const int ascol = (achk ^ ((arow >> 1) & 3)) * 8;
    const u16* a_h = Ahg + (size_t)(m0 + arow) * H_ + ascol;
    const int brow0 = arow,        bscol0 = (achk ^ ((brow0 >> 1) & 3)) * 8;
    const int brow1 = 128 + arow,  bscol1 = (achk ^ ((brow1 >> 1) & 3)) * 8;
    const u16* b_h0 = Bhg + (size_t)(n0 + brow0) * H_ + bscol0;
    const u16* b_h1 = Bhg + (size_t)(n0 + brow1) * H_ + bscol1;
    const int tid16 = tid * 16;
    const int aswz = (r16 >> 1) & 3;

    int aoff[4], boff[4];
#pragma unroll
    for (int i = 0; i < 4; i++) {
        aoff[i] = (wr * 64 + i * 16 + r16) * 32 + ((quad ^ aswz) * 8);
        boff[i] = (wc * 64 + i * 16 + r16) * 32 + ((quad ^ aswz) * 8);
    }

    // Prologue: stage tiles 0 and 1; wait only for tile 0 (vmcnt(3)).
    G1_STAGE(Ah0, Bh0, 0);
    G1_STAGE(Ah1, Bh1, 32);
    asm volatile("s_waitcnt vmcnt(3)" ::: "memory");
    __builtin_amdgcn_s_barrier();

    for (int t = 0; t < 32; t += 2) {
        G1_ITER(Ah0, Bh0, t);
        G1_ITER(Ah1, Bh1, t + 1);
    }

    // C/D layout: row = quad*4 + reg, col = lane&15; fp32 store (proven)
#pragma unroll
    for (int i = 0; i < 4; i++) {
        int gm = m0 + wr * 64 + i * 16 + quad * 4;
#pragma unroll
        for (int j = 0; j < 4; j++) {
            int gn = n0 + wc * 64 + j * 16 + r16;
            if (gn < DP1) {
#pragma unroll
                for (int reg = 0; reg < 4; reg++)
                    C[(size_t)(gm + reg) * DP1 + gn] = acc[i][j][reg];
            }
        }
    }
}

// ---------- softmax + candidate export (bf16-precision logits) ----------
// One block per (b,l) row, 1024 threads. Aligned vector I/O (head fix-up a0).
// Candidate criterion: e > sum*1e-8 (margin for bf16 logit error ~0.06).
// Non-candidate true p < ~4e-8 -> bf16-based p is within 1e-7 of reference.
__global__ __launch_bounds__(1024)
void softmax_cand_k(float* __restrict__ sim, int* __restrict__ gcnt,
                    int* __restrict__ gcidx) {
    __shared__ float red[16];
    __shared__ int   cnt;
    __shared__ int   cidx[GC];
    const int tid = threadIdx.x;
    const int row = blockIdx.x;
    float* rowp = sim + (size_t)row * DP1;
    if (tid == 0) cnt = 0;

    const int a0 = (4 - (row & 3)) & 3;          // head elems for 16B alignment
    const int b0 = a0 + tid * 4;
    const int b1 = a0 + 4096 + tid * 4;
    const int b2 = a0 + 8192 + tid * 4;

    float vh = (tid < a0) ? rowp[tid] : -3.4e38f;
    f32x4 v0 = *(const f32x4*)(rowp + b0);
    f32x4 v1 = *(const f32x4*)(rowp + b1);
    f32x4 v2;
    if (b2 + 3 <= D_) {
        v2 = *(const f32x4*)(rowp + b2);
    } else {
#pragma unroll
        for (int e = 0; e < 4; e++)
            v2[e] = (b2 + e <= D_) ? rowp[b2 + e] : -3.4e38f;
    }

    float mx = vh;
#pragma unroll
    for (int e = 0; e < 4; e++) mx = fmaxf(mx, fmaxf(v0[e], fmaxf(v1[e], v2[e])));
#pragma unroll
    for (int off = 32; off; off >>= 1) mx = fmaxf(mx, __shfl_down(mx, off, 64));
    if ((tid & 63) == 0) red[tid >> 6] = mx;
    __syncthreads();
#pragma unroll
    for (int w = 0; w < 16; w++) mx = fmaxf(mx, red[w]);

    float s0 = 0.f;
    vh = __expf(vh - mx); s0 += vh;
#pragma unroll
    for (int e = 0; e < 4; e++) {
        v0[e] = __expf(v0[e] - mx); s0 += v0[e];
        v1[e] = __expf(v1[e] - mx); s0 += v1[e];
        v2[e] = __expf(v2[e] - mx); s0 += v2[e];    // exp(-huge)=0 for pad
    }
#pragma unroll
    for (int off = 32; off; off >>= 1) s0 += __shfl_down(s0, off, 64);
    __syncthreads();                                // red[] reuse hazard
    if ((tid & 63) == 0) red[tid >> 6] = s0;
    __syncthreads();
    float sum = 0.f;
#pragma unroll
    for (int w = 0; w < 16; w++) sum += red[w];
    const float inv = 1.f / sum;
    const float thr = sum * 1e-8f;

    // write bf16-based probs + collect candidate indices (d < D_)
    if (tid < a0) {
        float p = vh * inv;
        rowp[tid] = p;
        if (vh > thr) {
            int k = atomicAdd(&cnt, 1);
            if (k < GC) cidx[k] = tid;
        }
    }
    {
        f32x4 p0 = v0 * inv;
        *(f32x4*)(rowp + b0) = p0;
#pragma unroll
        for (int e = 0; e < 4; e++)
            if (v0[e] > thr) {
                int k = atomicAdd(&cnt, 1);
                if (k < GC) cidx[k] = b0 + e;
            }
        f32x4 p1 = v1 * inv;
        *(f32x4*)(rowp + b1) = p1;
#pragma unroll
        for (int e = 0; e < 4; e++)
            if (v1[e] > thr) {
                int k = atomicAdd(&cnt, 1);
                if (k < GC) cidx[k] = b1 + e;
            }
#pragma unroll
        for (int e = 0; e < 4; e++) {
            int idx = b2 + e;
            if (idx <= D_) {
                float p = v2[e] * inv;
                rowp[idx] = p;                       // D_ overwritten exactly in gather
                if (idx < D_ && v2[e] > thr) {
                    int k = atomicAdd(&cnt, 1);
                    if (k < GC) cidx[k] = idx;
                }
            }
        }
    }
    __syncthreads();

    const int k = cnt < GC ? cnt : GC;
    if (tid < k) gcidx[(size_t)row * GC + tid] = cidx[tid];
    if (tid == 0) gcnt[row] = cnt;
}

// ---------- exact sparse finish: fp32 logits for candidates + default ----------
// Per row: recompute l_c = desc[row].vocab[d_c] (and l_def = desc[row].defe)
// exactly in fp32 (wave-parallel dots), rebuild max/Z/p from exact values,
// scatter exact p into sim, emit out = p_def*desc + sum p_c*vocab[d_c].
__global__ __launch_bounds__(256)
void gather_k(float* __restrict__ sim, const int* __restrict__ gcnt,
              const int* __restrict__ gcidx,
              const float* __restrict__ vocab, const float* __restrict__ defe,
              const float* __restrict__ desc, float* __restrict__ out) {
    __shared__ float lex[GC + 1];
    __shared__ float psh[GC + 1];
    const int tid = threadIdx.x;
    const int row = blockIdx.x;
    const int cnt0 = gcnt[row];
    const int cnt = cnt0 < GC ? cnt0 : GC;
    const float* drow = desc + (size_t)row * H_;
    const int lane = tid & 63, wv = tid >> 6;
    const int* crow = gcidx + (size_t)row * GC;

    // exact logits: wave wv handles candidates c = wv, wv+4, ...; c==cnt => default
    for (int c = wv; c <= cnt; c += 4) {
        const float* vrow = (c == cnt) ? defe : (vocab + (size_t)crow[c] * H_);
        float s = 0.f;
#pragma unroll
        for (int q = 0; q < 4; q++) {
            f32x4 dv = *(const f32x4*)(drow + (q * 64 + lane) * 4);
            f32x4 vv = *(const f32x4*)(vrow + (q * 64 + lane) * 4);
            s += dv[0] * vv[0] + dv[1] * vv[1] + dv[2] * vv[2] + dv[3] * vv[3];
        }
#pragma unroll
        for (int off = 32; off; off >>= 1) s += __shfl_down(s, off, 64);
        if (lane == 0) lex[c] = s;
    }
    __syncthreads();

    // exact max / Z over cnt+1 entries (tiny; redundant per-thread from LDS)
    float m = -3.4e38f;
    for (int c = 0; c <= cnt; c++) m = fmaxf(m, lex[c]);
    float Z = 0.f;
    for (int c = 0; c <= cnt; c++) Z += __expf(lex[c] - m);
    const float invZ = 1.f / Z;
    for (int i = tid; i <= cnt; i += 256) psh[i] = __expf(lex[i] - m) * invZ;
    __syncthreads();

    // scatter exact p into sim (candidates + default slot)
    float* rowp = sim + (size_t)row * DP1;
    for (int c = tid; c < cnt; c += 256) rowp[crow[c]] = psh[c];
    if (tid == 0) rowp[D_] = psh[cnt];

    // output: thread t owns 4 consecutive H-columns
    f32x4 a = psh[cnt] * ((const f32x4*)drow)[tid];
    if (cnt0 <= GC) {
        for (int c = 0; c < cnt; c++)
            a += psh[c] * ((const f32x4*)(vocab + (size_t)crow[c] * H_))[tid];
    } else {
        // overflow fallback (never on this data): full scan of bf16-based probs
        for (int d = 0; d < D_; d++) {
            float p = rowp[d];
            if (p > 1e-8f) a += p * ((const f32x4*)(vocab + (size_t)d * H_))[tid];
        }
    }
    ((f32x4*)(out + (size_t)row * H_))[tid] = a;
}

// ---------- fallback (ws too small): exact fp32 logits + fused epilogue ----------
__global__ __launch_bounds__(256)
void naive_logits_k(const float* __restrict__ vocab, const float* __restrict__ desc,
                    const float* __restrict__ defe, float* __restrict__ sim) {
    int d = blockIdx.x * 256 + threadIdx.x;
    if (d >= DP1) return;
    const float* vr = (d < D_) ? (vocab + (size_t)d * H_) : defe;
    const float* dr = desc + (size_t)blockIdx.y * H_;
    float s = 0.f;
    for (int h = 0; h < H_; h++) s = fmaf(dr[h], vr[h], s);
    sim[(size_t)blockIdx.y * DP1 + d] = s;
}

__global__ __launch_bounds__(1024)
void softmax_gather_k(float* __restrict__ sim, const float* __restrict__ vocab,
                      const float* __restrict__ desc, float* __restrict__ out) {
    __shared__ float red[16];
    __shared__ float wslot;
    __shared__ int   cnt;
    __shared__ int   cidx[CANDS];
    __shared__ float cp[CANDS];
    const int tid = threadIdx.x;
    const int row = blockIdx.x;
    float* rowp = sim + (size_t)row * DP1;
    if (tid == 0) cnt = 0;

    const int a0 = (4 - (row & 3)) & 3;
    const int b0 = a0 + tid * 4;
    const int b1 = a0 + 4096 + tid * 4;
    const int b2 = a0 + 8192 + tid * 4;

    float vh = (tid < a0) ? rowp[tid] : -3.4e38f;
    f32x4 v0 = *(const f32x4*)(rowp + b0);
    f32x4 v1 = *(const f32x4*)(rowp + b1);
    f32x4 v2;
    if (b2 + 3 <= D_) {
        v2 = *(const f32x4*)(rowp + b2);
    } else {
#pragma unroll
        for (int e = 0; e < 4; e++)
            v2[e] = (b2 + e <= D_) ? rowp[b2 + e] : -3.4e38f;
    }

    float mx = vh;
#pragma unroll
    for (int e = 0; e < 4; e++) mx = fmaxf(mx, fmaxf(v0[e], fmaxf(v1[e], v2[e])));
#pragma unroll
    for (int off = 32; off; off >>= 1) mx = fmaxf(mx, __shfl_down(mx, off, 64));
    if ((tid & 63) == 0) red[tid >> 6] = mx;
    __syncthreads();
#pragma unroll
    for (int w = 0; w < 16; w++) mx = fmaxf(mx, red[w]);

    float s0 = 0.f;
    vh = __expf(vh - mx); s0 += vh;
#pragma unroll
    for (int e = 0; e < 4; e++) {
        v0[e] = __expf(v0[e] - mx); s0 += v0[e];
        v1[e] = __expf(v1[e] - mx); s0 += v1[e];
        v2[e] = __expf(v2[e] - mx); s0 += v2[e];
    }
#pragma unroll
    for (int off = 32; off; off >>= 1) s0 += __shfl_down(s0, off, 64);
    __syncthreads();
    if ((tid & 63) == 0) red[tid >> 6] = s0;
    __syncthreads();
    float sum = 0.f;
#pragma unroll
    for (int w = 0; w < 16; w++) sum += red[w];
    const float inv = 1.f / sum;
    const float thr = sum * 1e-7f;

    if (tid < a0) {
        float p = vh * inv;
        rowp[tid] = p;
        if (vh > thr) {
            int k = atomicAdd(&cnt, 1);
            if (k < CANDS) { cidx[k] = tid; cp[k] = p; }
        }
    }
    {
        f32x4 p0 = v0 * inv;
        *(f32x4*)(rowp + b0) = p0;
#pragma unroll
        for (int e = 0; e < 4; e++)
            if (v0[e] > thr) {
                int k = atomicAdd(&cnt, 1);
                if (k < CANDS) { cidx[k] = b0 + e; cp[k] = p0[e]; }
            }
        f32x4 p1 = v1 * inv;
        *(f32x4*)(rowp + b1) = p1;
#pragma unroll
        for (int e = 0; e < 4; e++)
            if (v1[e] > thr) {
                int k = atomicAdd(&cnt, 1);
                if (k < CANDS) { cidx[k] = b1 + e; cp[k] = p1[e]; }
            }
#pragma unroll
        for (int e = 0; e < 4; e++) {
            int idx = b2 + e;
            if (idx <= D_) {
                float p = v2[e] * inv;
                rowp[idx] = p;
                if (idx == D_) wslot = p;
                else if (v2[e] > thr) {
                    int k = atomicAdd(&cnt, 1);
                    if (k < CANDS) { cidx[k] = idx; cp[k] = p; }
                }
            }
        }
    }
    __syncthreads();

    const float w = wslot;
    float a = w * desc[(size_t)row * H_ + tid];
    if (cnt <= CANDS) {
        const int k = cnt;
        for (int c = 0; c < k; c++)
            a += cp[c] * vocab[(size_t)cidx[c] * H_ + tid];
    } else {
        const float pthr = thr * inv;
        for (int d = 0; d < D_; d++) {
            float p = rowp[d];
            if (p > pthr) a += p * vocab[(size_t)d * H_ + tid];
        }
    }
    out[(size_t)row * H_ + tid] = a;
}

extern "C" void kernel_launch(void* const* d_in, const int* in_sizes, int n_in,
                              void* d_out, int out_size, void* d_ws, size_t ws_size,
                              hipStream_t stream) {
    (void)in_sizes; (void)n_in; (void)out_size;
    const float* vocab = (const float*)d_in[0];
    const float* desc  = (const float*)d_in[1];
    const float* defe  = (const float*)d_in[2];
    float* out = (float*)d_out;                          // concept: [4096][1024]
    float* sim = out + (size_t)BL * H_;                  // sim:     [4096][10001]

    // ws layout (bytes):
    //   desc_bf @ 0          (8,388,608)
    //   fv_bf   @ 8,388,608  (20,971,520 = NPAD2*H_*2) -> REQ = 29,360,128
    // After gemm1 the split arrays are dead; candidate lists reuse ws+0:
    //   gcnt  @ 0       (16,384)
    //   gcidx @ 32,768  (8,388,608 = BL*GC*4)
    const size_t REQ = 29360128ull;
    char* ws = (char*)d_ws;

    if (ws_size >= REQ) {
        u16* dhi = (u16*)(ws + 0);
        u16* fhi = (u16*)(ws + 8388608);

        split_all_k<<<7168, 256, 0, stream>>>(desc, vocab, defe, dhi, fhi);
        gemm1_k<<<dim3(40, 32), 512, 0, stream>>>(dhi, fhi, sim);

        int* gcnt  = (int*)(ws + 0);
        int* gcidx = (int*)(ws + 32768);
        softmax_cand_k<<<4096, 1024, 0, stream>>>(sim, gcnt, gcidx);
        gather_k<<<4096, 256, 0, stream>>>(sim, gcnt, gcidx, vocab, defe, desc, out);
    } else {
        naive_logits_k<<<dim3(40, BL), 256, 0, stream>>>(vocab, desc, defe, sim);
        softmax_gather_k<<<4096, 1024, 0, stream>>>(sim, vocab, desc, out);
    }
}